// Round 1
// baseline (219.454 us; speedup 1.0000x reference)
//
#include <hip/hip_runtime.h>

// ContrastLoss: three 256-bin smooth (Gaussian, sigma=0.01) histograms over
// 262144-element images, then scalar MSE-style loss between them.
//
// sigma = 0.01 = 2.55 bin widths (bin width = 1/255). Truncating the Gaussian
// window to +/-20 bins gives relative error ~2e-13 -> exact in f32.

constexpr int BINS = 256;
constexpr int WIN  = 20;            // +/-20 bins
constexpr int TAPS = 2 * WIN + 1;   // 41

__global__ __launch_bounds__(256)
void hist3_kernel(const float* __restrict__ im0,
                  const float* __restrict__ im1,
                  const float* __restrict__ im2,
                  float* __restrict__ hist,     // [3][BINS], pre-zeroed
                  int n_per_img, int blocks_per_img)
{
    __shared__ float h[BINS];
    const int img = blockIdx.x / blocks_per_img;
    const int blk = blockIdx.x - img * blocks_per_img;
    const float* __restrict__ src = (img == 0) ? im0 : (img == 1) ? im1 : im2;

    h[threadIdx.x] = 0.0f;          // blockDim.x == BINS == 256
    __syncthreads();

    const float inv255 = 1.0f / 255.0f;

    // Grid-stride over pixels of this image (coalesced scalar f32 loads;
    // total input is only 3 MiB so vector width is not the lever here).
    for (int i = blk * 256 + threadIdx.x; i < n_per_img;
         i += blocks_per_img * 256) {
        const float x  = src[i];
        const int   jc = __float2int_rn(x * 255.0f);

        // 41-tap window, fully unrolled: w[] indices are compile-time
        // constants -> stays in VGPRs (no scratch).
        float w[TAPS];
        float s = 0.0f;
        #pragma unroll
        for (int t = 0; t < TAPS; ++t) {
            const int   j = jc - WIN + t;
            const float d = (x - (float)j * inv255) * 100.0f;   // (x-c)/sigma
            float g = __expf(-0.5f * d * d);
            if (j < 0 || j >= BINS) g = 0.0f;                   // clamp to range
            w[t] = g;
            s += g;
        }
        const float inv = 1.0f / (s + 1e-8f);

        #pragma unroll
        for (int t = 0; t < TAPS; ++t) {
            const int j = jc - WIN + t;
            if (j >= 0 && j < BINS)
                atomicAdd(&h[j], w[t] * inv);
        }
    }

    __syncthreads();
    // One global atomic per bin per block: 768 blocks -> 256 same-address
    // atomics per bin, negligible contention.
    atomicAdd(&hist[img * BINS + threadIdx.x], h[threadIdx.x]);
}

__global__ __launch_bounds__(BINS)
void loss_kernel(const float* __restrict__ hist, float* __restrict__ out)
{
    const int j  = threadIdx.x;
    const float hf = hist[j];
    const float hi = hist[BINS + j];
    const float hv = hist[2 * BINS + j];
    const float a = hf - hi;
    const float b = hf - hv;
    float v = 0.5f * a * a + 0.5f * b * b;

    // 64-lane wave reduce, then 4 wave partials via LDS.
    #pragma unroll
    for (int off = 32; off > 0; off >>= 1)
        v += __shfl_down(v, off);

    __shared__ float partial[4];
    if ((j & 63) == 0) partial[j >> 6] = v;
    __syncthreads();
    if (j == 0) {
        const float t = partial[0] + partial[1] + partial[2] + partial[3];
        out[0] = t * (1.0f / (float)BINS);   // mean over bins
    }
}

extern "C" void kernel_launch(void* const* d_in, const int* in_sizes, int n_in,
                              void* d_out, int out_size, void* d_ws, size_t ws_size,
                              hipStream_t stream)
{
    const float* fused = (const float*)d_in[0];
    const float* ir    = (const float*)d_in[1];
    const float* vis   = (const float*)d_in[2];
    float* hist = (float*)d_ws;                 // [3][BINS] f32
    float* out  = (float*)d_out;

    const int n = in_sizes[0];                  // 262144 per image

    // d_ws is poisoned to 0xAA before every launch -> must zero.
    hipMemsetAsync(hist, 0, 3 * BINS * sizeof(float), stream);

    // 4 pixels/thread: 256 blocks per image at n=262144.
    const int blocks_per_img = (n + (256 * 4) - 1) / (256 * 4);
    hist3_kernel<<<dim3(3 * blocks_per_img), 256, 0, stream>>>(
        fused, ir, vis, hist, n, blocks_per_img);

    loss_kernel<<<1, BINS, 0, stream>>>(hist, out);
}

// Round 2
// 219.174 us; speedup vs baseline: 1.0013x; 1.0013x over previous
//
#include <hip/hip_runtime.h>

// ContrastLoss: three 256-bin smooth (Gaussian, sigma=0.01) histograms over
// 262144-element images, then scalar MSE-style loss between them.
//
// sigma = 0.01 = 2.55 bin widths (bin width = 1/255). Truncating the Gaussian
// window to +/-20 bins gives relative error ~2e-13 -> exact in f32.
//
// R1 change: the R0 kernel kept all 41 tap weights live between the
// normalize and accumulate loops -> w[41] spilled to scratch (VGPR_Count=48,
// VALUBusy 7%, 162us of pure latency). Now we RECOMPUTE g in pass 2 with a
// bit-identical instruction sequence instead of storing it. Live state per
// pixel is ~4 registers. Also: per-wave LDS histogram replicas (kill
// cross-wave same-address atomic serialization) and 2 px/thread for ~24
// waves/CU of latency hiding.

constexpr int BINS = 256;
constexpr int WIN  = 20;            // +/-20 bins
constexpr int TAPS = 2 * WIN + 1;   // 41
constexpr int WAVES_PER_BLOCK = 4;  // 256 threads

__global__ __launch_bounds__(256)
void hist3_kernel(const float* __restrict__ im0,
                  const float* __restrict__ im1,
                  const float* __restrict__ im2,
                  float* __restrict__ hist,     // [3][BINS], pre-zeroed
                  int n_per_img, int blocks_per_img)
{
    __shared__ float h[WAVES_PER_BLOCK][BINS];  // per-wave replica, 4 KiB
    const int img = blockIdx.x / blocks_per_img;
    const int blk = blockIdx.x - img * blocks_per_img;
    const float* __restrict__ src = (img == 0) ? im0 : (img == 1) ? im1 : im2;

    const int tid  = threadIdx.x;
    const int wave = tid >> 6;
    float* __restrict__ hw = h[wave];

    #pragma unroll
    for (int k = 0; k < WAVES_PER_BLOCK; ++k)
        h[k][tid] = 0.0f;
    __syncthreads();

    const float inv255 = 1.0f / 255.0f;

    for (int i = blk * 256 + tid; i < n_per_img; i += blocks_per_img * 256) {
        const float x  = src[i];
        const int   jc = __float2int_rn(x * 255.0f);

        // Pass 1: normalization sum only — nothing kept live but s.
        float s = 0.0f;
        #pragma unroll
        for (int t = 0; t < TAPS; ++t) {
            const int   j = jc - WIN + t;
            const float d = (x - (float)j * inv255) * 100.0f;   // (x-c)/sigma
            float g = __expf(-0.5f * d * d);
            if (j < 0 || j >= BINS) g = 0.0f;
            s += g;
        }
        const float inv = 1.0f / (s + 1e-8f);

        // Pass 2: recompute g (identical sequence -> bit-identical) and
        // scatter into this wave's LDS histogram replica.
        #pragma unroll
        for (int t = 0; t < TAPS; ++t) {
            const int   j = jc - WIN + t;
            const float d = (x - (float)j * inv255) * 100.0f;
            const float g = __expf(-0.5f * d * d);
            if (j >= 0 && j < BINS)
                atomicAdd(&hw[j], g * inv);
        }
    }

    __syncthreads();
    // Merge the 4 wave replicas, one global atomic per bin per block.
    const float v = h[0][tid] + h[1][tid] + h[2][tid] + h[3][tid];
    atomicAdd(&hist[img * BINS + tid], v);
}

__global__ __launch_bounds__(BINS)
void loss_kernel(const float* __restrict__ hist, float* __restrict__ out)
{
    const int j  = threadIdx.x;
    const float hf = hist[j];
    const float hi = hist[BINS + j];
    const float hv = hist[2 * BINS + j];
    const float a = hf - hi;
    const float b = hf - hv;
    float v = 0.5f * a * a + 0.5f * b * b;

    #pragma unroll
    for (int off = 32; off > 0; off >>= 1)
        v += __shfl_down(v, off);

    __shared__ float partial[4];
    if ((j & 63) == 0) partial[j >> 6] = v;
    __syncthreads();
    if (j == 0) {
        const float t = partial[0] + partial[1] + partial[2] + partial[3];
        out[0] = t * (1.0f / (float)BINS);   // mean over bins
    }
}

extern "C" void kernel_launch(void* const* d_in, const int* in_sizes, int n_in,
                              void* d_out, int out_size, void* d_ws, size_t ws_size,
                              hipStream_t stream)
{
    const float* fused = (const float*)d_in[0];
    const float* ir    = (const float*)d_in[1];
    const float* vis   = (const float*)d_in[2];
    float* hist = (float*)d_ws;                 // [3][BINS] f32
    float* out  = (float*)d_out;

    const int n = in_sizes[0];                  // 262144 per image

    // d_ws is poisoned to 0xAA before every launch -> must zero.
    hipMemsetAsync(hist, 0, 3 * BINS * sizeof(float), stream);

    // 2 pixels/thread: 512 blocks per image at n=262144 -> 1536 blocks total,
    // ~24 waves/CU for latency hiding.
    const int blocks_per_img = (n + (256 * 2) - 1) / (256 * 2);
    hist3_kernel<<<dim3(3 * blocks_per_img), 256, 0, stream>>>(
        fused, ir, vis, hist, n, blocks_per_img);

    loss_kernel<<<1, BINS, 0, stream>>>(hist, out);
}

// Round 7
// 107.781 us; speedup vs baseline: 2.0361x; 2.0335x over previous
//
#include <hip/hip_runtime.h>

// ContrastLoss: three 256-bin Gaussian-smoothed (sigma=0.01) histograms over
// 262144-px images + scalar MSE-style loss.
//
// R2 change: R0/R1 were limited by scattered LDS atomicAdd throughput
// (~2.9 cyc per lane-atomic per CU; 32M lane-atomics ~= 150us; address
// distribution irrelevant — R0 shared vs R1 replicated LDS identical).
// Now: ZERO atomics in the hot loop. Each wave keeps the full 256-bin
// histogram in 4 VGPRs/lane (lane l owns bins l, l+64, l+128, l+192).
// Window (+-20 bins) is narrower than 64, so each lane has at most ONE
// owned bin in any pixel's window: k = (jc+32-lane)>>6 selects it.
// Per 64-px wave batch: register-only normalization pass (own pixel),
// then 64 v_readlane broadcast steps, each lane FMAs into its register
// histogram. Merge via plain LDS writes + 1 global atomic per bin/block.

constexpr int BINS = 256;
constexpr int WIN  = 20;            // +/-20 bins; tail < 1e-14 relative
constexpr int TAPS = 2 * WIN + 1;   // 41

__global__ __launch_bounds__(256)
void hist3_kernel(const float* __restrict__ im0,
                  const float* __restrict__ im1,
                  const float* __restrict__ im2,
                  float* __restrict__ hist,     // [3][BINS], pre-zeroed
                  int n_per_img, int blocks_per_img)
{
    const int img = blockIdx.x / blocks_per_img;
    const int blk = blockIdx.x - img * blocks_per_img;
    const float* __restrict__ src = (img == 0) ? im0 : (img == 1) ? im1 : im2;

    const int tid  = threadIdx.x;
    const int lane = tid & 63;
    const int wave = tid >> 6;

    // d = (x - j/255)*100  ->  -0.5*d*d = (t255 - j)^2 * Ce,  t255 = x*255
    const float Ce = -0.5f * (100.0f / 255.0f) * (100.0f / 255.0f);

    float acc0 = 0.0f, acc1 = 0.0f, acc2 = 0.0f, acc3 = 0.0f;

    const int stride = blocks_per_img * 256;
    for (int base = blk * 256; base < n_per_img; base += stride) {
        const int i = base + tid;
        float x = 2.0f;                 // sentinel: jc=510 -> s=0, k=7 -> no deposit
        if (i < n_per_img) x = src[i];

        const float t255 = x * 255.0f;
        const int   jc   = __float2int_rn(t255);

        // Pass 1: this lane's own normalization sum (registers only).
        float s = 0.0f;
        const float dd0 = t255 - (float)(jc - WIN);
        #pragma unroll
        for (int t = 0; t < TAPS; ++t) {
            const int   j  = jc - WIN + t;
            const float dd = dd0 - (float)t;
            const float e  = __expf(dd * dd * Ce);
            s += ((unsigned)j <= 255u) ? e : 0.0f;
        }
        const float inv = 1.0f / (s + 1e-8f);

        // Broadcast-gather: walk the wave's 64 pixels; every lane deposits
        // its (single) in-window owned bin into registers. No LDS, no sync.
        #pragma unroll
        for (int p = 0; p < 64; ++p) {
            const float sx = __int_as_float(
                __builtin_amdgcn_readlane(__float_as_int(t255), p));
            const float si = __int_as_float(
                __builtin_amdgcn_readlane(__float_as_int(inv), p));
            const int jcp = __float2int_rn(sx);
            const int k   = (jcp + 32 - lane) >> 6;   // round((jcp-lane)/64)
            const int j   = lane + (k << 6);          // candidate owned bin
            const float dd  = sx - (float)j;
            const float e   = __expf(dd * dd * Ce);   // ~0 if out of window
            const float val = e * si;
            acc0 += (k == 0) ? val : 0.0f;            // k outside [0,3] (incl.
            acc1 += (k == 1) ? val : 0.0f;            // sentinel/edge) deposits
            acc2 += (k == 2) ? val : 0.0f;            // nowhere -> bins 0..255 only
            acc3 += (k == 3) ? val : 0.0f;
        }
    }

    // Merge the 4 waves' register histograms via plain LDS, then one global
    // atomic per bin per block (256 blocks/img -> 256 adds per address).
    __shared__ float m[4][BINS];
    m[wave][lane]       = acc0;
    m[wave][lane + 64]  = acc1;
    m[wave][lane + 128] = acc2;
    m[wave][lane + 192] = acc3;
    __syncthreads();
    const float v = m[0][tid] + m[1][tid] + m[2][tid] + m[3][tid];
    atomicAdd(&hist[img * BINS + tid], v);
}

__global__ __launch_bounds__(BINS)
void loss_kernel(const float* __restrict__ hist, float* __restrict__ out)
{
    const int j  = threadIdx.x;
    const float hf = hist[j];
    const float hi = hist[BINS + j];
    const float hv = hist[2 * BINS + j];
    const float a = hf - hi;
    const float b = hf - hv;
    float v = 0.5f * a * a + 0.5f * b * b;

    #pragma unroll
    for (int off = 32; off > 0; off >>= 1)
        v += __shfl_down(v, off);

    __shared__ float partial[4];
    if ((j & 63) == 0) partial[j >> 6] = v;
    __syncthreads();
    if (j == 0) {
        const float t = partial[0] + partial[1] + partial[2] + partial[3];
        out[0] = t * (1.0f / (float)BINS);   // mean over bins
    }
}

extern "C" void kernel_launch(void* const* d_in, const int* in_sizes, int n_in,
                              void* d_out, int out_size, void* d_ws, size_t ws_size,
                              hipStream_t stream)
{
    const float* fused = (const float*)d_in[0];
    const float* ir    = (const float*)d_in[1];
    const float* vis   = (const float*)d_in[2];
    float* hist = (float*)d_ws;                 // [3][BINS] f32
    float* out  = (float*)d_out;

    const int n = in_sizes[0];                  // 262144 per image

    // d_ws is poisoned to 0xAA before every launch -> must zero.
    hipMemsetAsync(hist, 0, 3 * BINS * sizeof(float), stream);

    // 256 blocks/img (768 total = 3 blocks/CU, 12 waves/CU): VALU-throughput
    // kernel; 4 px/thread amortizes the final merge.
    const int blocks_per_img = 256;
    hist3_kernel<<<dim3(3 * blocks_per_img), 256, 0, stream>>>(
        fused, ir, vis, hist, n, blocks_per_img);

    loss_kernel<<<1, BINS, 0, stream>>>(hist, out);
}